// Round 1
// 374.819 us; speedup vs baseline: 1.1745x; 1.1745x over previous
//
#include <hip/hip_runtime.h>
#include <stdint.h>

#define B_ 2
#define M_ 4096
#define N_ 4096
#define K_ 4096
#define WPR 128        // u32 words per packed row (K/32)
#define NIT 32         // K iterations: 128 bits (4 words) per iteration
#define TM 128
#define TN 128
#define LDR 80         // LDS row stride bytes (64 nibble-data + 16 pad, 16B-aligned)

typedef int v4i   __attribute__((ext_vector_type(4)));
typedef int v8i   __attribute__((ext_vector_type(8)));
typedef float v16f __attribute__((ext_vector_type(16)));

// ---------------- pack rows to sign bits ----------------
// Half-wave (32 lanes) packs one row (4096 floats -> 128 u32 words, bit =
// sign bit). Fixed within-row K-permutation, identical for x and y (the
// binary dot product is invariant under a shared K-permutation).
__global__ __launch_bounds__(256) void pack_rows(
    const float* __restrict__ x, const float* __restrict__ y,
    uint32_t* __restrict__ px, uint32_t* __restrict__ py) {
    const float* in = blockIdx.y ? y : x;
    uint32_t* out   = blockIdx.y ? py : px;
    const int wid  = (blockIdx.x * blockDim.x + threadIdx.x) >> 6;  // 0..4095
    const int half = (threadIdx.x >> 5) & 1;
    const int l    = threadIdx.x & 31;
    const int row  = wid * 2 + half;  // 0..8191
    const float4* src = (const float4*)(in + (size_t)row * K_);
    uint32_t r0 = 0, r1 = 0, r2 = 0, r3 = 0;
#pragma unroll 8
    for (int j = 0; j < 32; ++j) {
        float4 f = src[j * 32 + l];
        r0 = (r0 << 1) | (__float_as_uint(f.x) >> 31);
        r1 = (r1 << 1) | (__float_as_uint(f.y) >> 31);
        r2 = (r2 << 1) | (__float_as_uint(f.z) >> 31);
        r3 = (r3 << 1) | (__float_as_uint(f.w) >> 31);
    }
    ((uint4*)(out + (size_t)row * WPR))[l] = make_uint4(r0, r1, r2, r3);
}

// ---------------- fp4 MFMA binary GEMM ----------------
// sign(x).sign(y)^T computed EXACTLY with v_mfma_scale_f32_32x32x64_f8f6f4:
// bit b -> fp4 nibble 0x2|(b<<3) = +/-1.0 (e2m1), e8m0 scale 0x7F = 1.0,
// fp32 accumulation -> out = clipscale * acc directly (no popcount correction).
// 128x128 tile, 4 waves, each wave 2x2 tiles of 32x32. Per iteration: 128 bits
// of K (4 words/row) expanded to 64 nibble-bytes/row in LDS; double-buffered,
// one barrier per 128-bit iteration. Within-word nibble permutation is the
// same bijection for A and B -> dot product unchanged.
__global__ __launch_bounds__(256, 4) void bgemm_fp4(
    const uint32_t* __restrict__ pxw, const uint32_t* __restrict__ pyw,
    float* __restrict__ out, const float* __restrict__ xclip,
    const float* __restrict__ yclip) {
    __shared__ uint8_t As[2][TM * LDR];
    __shared__ uint8_t Bs[2][TN * LDR];

    const int b    = blockIdx.z;
    const int m0   = blockIdx.x * TM;
    const int n0   = blockIdx.y * TN;
    const int t    = threadIdx.x;
    const int lane = t & 63;
    const int w    = t >> 6;
    const int wr   = w >> 1, wc = w & 1;

    // expansion source: row er = t>>1, word-pair wh = t&1 (words 4c+2wh+{0,1})
    const int er = t >> 1;
    const int wh = t & 1;
    const uint32_t* gA = pxw + ((size_t)(b * M_ + m0 + er)) * WPR + 2 * wh;
    const uint32_t* gB = pyw + ((size_t)(b * N_ + n0 + er)) * WPR + 2 * wh;

    v16f acc[2][2];
#pragma unroll
    for (int ti = 0; ti < 2; ++ti)
#pragma unroll
        for (int tj = 0; tj < 2; ++tj)
#pragma unroll
            for (int r = 0; r < 16; ++r) acc[ti][tj][r] = 0.0f;

    // expand 2 words (64 bits) -> 32 fp4 bytes: nibble = 0x2 | (bit<<3)
#define EXPAND_STORE(w2, base)                                               \
    {                                                                        \
        uint32_t _a = (w2).x, _b = (w2).y;                                   \
        uint4* p_ = (uint4*)((base) + er * LDR + wh * 32);                   \
        p_[0] = make_uint4(0x22222222u | ((_a & 0x11111111u) << 3),          \
                           0x22222222u | (((_a >> 1) & 0x11111111u) << 3),   \
                           0x22222222u | (((_a >> 2) & 0x11111111u) << 3),   \
                           0x22222222u | (((_a >> 3) & 0x11111111u) << 3));  \
        p_[1] = make_uint4(0x22222222u | ((_b & 0x11111111u) << 3),          \
                           0x22222222u | (((_b >> 1) & 0x11111111u) << 3),   \
                           0x22222222u | (((_b >> 2) & 0x11111111u) << 3),   \
                           0x22222222u | (((_b >> 3) & 0x11111111u) << 3));  \
    }

    uint2 wa = *(const uint2*)gA;
    uint2 wb = *(const uint2*)gB;
    EXPAND_STORE(wa, As[0]);
    EXPAND_STORE(wb, Bs[0]);
    __syncthreads();

    // fp4 operands live in v[0:3] of the 8-dword MFMA operand; upper 4 = 0.
    v8i a8[2], b8[2];
#pragma unroll
    for (int i = 0; i < 2; ++i)
#pragma unroll
        for (int j = 0; j < 8; ++j) { a8[i][j] = 0; b8[i][j] = 0; }

    const int hi16 = (lane >> 5) * 16;       // k-half select within row
    const int ar   = wr * 64 + (lane & 31);  // A row base for this lane
    const int br   = wc * 64 + (lane & 31);  // B row base for this lane

    for (int c = 0; c < NIT; ++c) {
        const int buf = c & 1;
        if (c + 1 < NIT) {  // prefetch next word-pairs (L2-hot, 8 MB footprint)
            wa = *(const uint2*)(gA + 4 * (c + 1));
            wb = *(const uint2*)(gB + 4 * (c + 1));
        }
#pragma unroll
        for (int ks = 0; ks < 2; ++ks) {
#pragma unroll
            for (int ti = 0; ti < 2; ++ti) {
                *(v4i*)&a8[ti] =
                    *(const v4i*)(&As[buf][(ar + ti * 32) * LDR + ks * 32 + hi16]);
                *(v4i*)&b8[ti] =
                    *(const v4i*)(&Bs[buf][(br + ti * 32) * LDR + ks * 32 + hi16]);
            }
#pragma unroll
            for (int ti = 0; ti < 2; ++ti)
#pragma unroll
                for (int tj = 0; tj < 2; ++tj)
                    acc[ti][tj] = __builtin_amdgcn_mfma_scale_f32_32x32x64_f8f6f4(
                        a8[ti], b8[tj], acc[ti][tj], 4, 4,   // fmtA=fp4, fmtB=fp4
                        0, 0x7F7F7F7F, 0, 0x7F7F7F7F);       // scales = 1.0 (e8m0 127)
        }
        if (c + 1 < NIT) {
            EXPAND_STORE(wa, As[buf ^ 1]);
            EXPAND_STORE(wb, Bs[buf ^ 1]);
        }
        __syncthreads();
    }

    // epilogue: C/D layout (32x32, shape-determined): col = lane&31,
    // row = (r&3) + 8*(r>>2) + 4*(lane>>5)
    const float scale = xclip[0] * yclip[0];
    const int col   = lane & 31;
    const int rquad = (lane >> 5) * 4;
#pragma unroll
    for (int ti = 0; ti < 2; ++ti) {
#pragma unroll
        for (int r = 0; r < 16; ++r) {
            int rowl = (r & 3) + 8 * (r >> 2) + rquad;
            int mm = m0 + wr * 64 + ti * 32 + rowl;
            float* orow = out + ((size_t)b * M_ + mm) * (size_t)N_;
#pragma unroll
            for (int tj = 0; tj < 2; ++tj) {
                int nn = n0 + wc * 64 + tj * 32 + col;
                orow[nn] = scale * acc[ti][tj][r];
            }
        }
    }
}

extern "C" void kernel_launch(void* const* d_in, const int* in_sizes, int n_in,
                              void* d_out, int out_size, void* d_ws, size_t ws_size,
                              hipStream_t stream) {
    const float* x     = (const float*)d_in[0];
    const float* y     = (const float*)d_in[1];
    const float* xclip = (const float*)d_in[2];
    const float* yclip = (const float*)d_in[3];
    float* out = (float*)d_out;

    // workspace: px 4MB | py 4MB  (requires ws >= 8MB)
    uint32_t* px = (uint32_t*)d_ws;
    uint32_t* py = px + (size_t)B_ * M_ * WPR;

    hipLaunchKernelGGL(pack_rows, dim3(1024, 2), dim3(256), 0, stream,
                       x, y, px, py);

    dim3 grid(M_ / TM, N_ / TN, B_);
    hipLaunchKernelGGL(bgemm_fp4, grid, dim3(256), 0, stream,
                       px, py, out, xclip, yclip);
}